// Round 9
// baseline (34.632 us; speedup 1.0000x reference)
//
#include <hip/hip_runtime.h>
#include <hip/hip_bf16.h>
#include <math.h>

#define N_Q 2048
#define M_K 1024
#define DIN 128
#define DK  64

typedef __attribute__((ext_vector_type(8))) short short8;
typedef __attribute__((ext_vector_type(4))) float f32x4;

// ---- LDS byte offsets (total 44448 B, static) ----
// main phase:   kph us[128][72] @0 | kpl @18432 | qrow f[8][132] @36864 |
//               qph us[8][72] @41088 | qpl @42240 | kn2c f[128] @43392 |
//               qn2s f[8] @43904 | redmax f[8][8] @43936 | redsum @44192
// prologue overlays in [0,36864): W_f32[8192] @0 ; then Wh us[64][136] @0, Wl @17408
#define OFF_KPH   0
#define OFF_KPL   18432
#define OFF_QROW  36864
#define OFF_QPH   41088
#define OFF_QPL   42240
#define OFF_KN2   43392
#define OFF_QN2   43904
#define OFF_RMAX  43936
#define OFF_RSUM  44192
#define SMEM_SZ   44448

// RNE bf16 hi/lo split of 8 fp32 -> two short8 frags (validated pack_split math)
static __device__ __forceinline__ void split8(const float* v, short8& h, short8& l)
{
    __attribute__((aligned(16))) unsigned int hu[4], lu[4];
    #pragma unroll
    for (int i = 0; i < 4; ++i) {
        __hip_bfloat16 h0 = __float2bfloat16(v[2*i]);
        __hip_bfloat16 h1 = __float2bfloat16(v[2*i+1]);
        float f0 = __bfloat162float(h0), f1 = __bfloat162float(h1);
        __hip_bfloat16 l0 = __float2bfloat16(v[2*i]   - f0);
        __hip_bfloat16 l1 = __float2bfloat16(v[2*i+1] - f1);
        hu[i] = (unsigned)*(unsigned short*)&h0 | ((unsigned)*(unsigned short*)&h1 << 16);
        lu[i] = (unsigned)*(unsigned short*)&l0 | ((unsigned)*(unsigned short*)&l1 << 16);
    }
    h = *(short8*)hu;
    l = *(short8*)lu;
}

// pack f32x4 -> 4 bf16-hi (2 dwords) + 4 bf16-lo (2 dwords)
static __device__ __forceinline__ void packpair(const f32x4& a, uint2& hi2, uint2& lo2)
{
    unsigned short hs[4], ls[4];
    #pragma unroll
    for (int j = 0; j < 4; ++j) {
        __hip_bfloat16 hb = __float2bfloat16(a[j]);
        float hf = __bfloat162float(hb);
        __hip_bfloat16 lb = __float2bfloat16(a[j] - hf);
        hs[j] = *(unsigned short*)&hb;
        ls[j] = *(unsigned short*)&lb;
    }
    hi2 = make_uint2(hs[0] | ((unsigned)hs[1] << 16), hs[2] | ((unsigned)hs[3] << 16));
    lo2 = make_uint2(ls[0] | ((unsigned)ls[1] << 16), ls[2] | ((unsigned)ls[3] << 16));
}

// ---------------------------------------------------------------------------
// ONE kernel, ZERO cross-block communication, no workspace.
// 256 blocks x 512 thr (8 waves). Block owns 8 q-rows x all 1024 m.
// Each block redundantly projects all k-rows with MFMA (3456 MFMA/block,
// ~7 us) -- trades 16x redundant matrix FLOPs for one dispatch boundary.
// All MFMA operand/output algebra identical to the R5/R8-validated pattern:
// A-frag lane(g,c) = X[c][8g..8g+7], B-frag = Y[c][8g..],
// D[row=4g+j (X-row)][col=c (Y-row)].
// ---------------------------------------------------------------------------
__global__ __launch_bounds__(512) void fused_kernel(
    const float* __restrict__ q, const float* __restrict__ k,
    const float* __restrict__ W, float* __restrict__ out)
{
    __shared__ __align__(16) unsigned char smem[SMEM_SZ];

    const int tx = threadIdx.x;
    const int w = tx >> 6, lane = tx & 63;
    const int g = lane >> 4, c = lane & 15;
    const int n0 = blockIdx.x * 8;

    // ---- P0: stage W fp32 (linear) + this block's 8 q rows ----
    {
        const float4* W4 = (const float4*)W;
        float4* Wst = (float4*)smem;
        #pragma unroll
        for (int i = 0; i < 4; ++i) Wst[tx + 512*i] = W4[tx + 512*i];
        if (tx < 256) {
            float4 v = ((const float4*)q)[((size_t)n0 + (tx>>5))*32 + (tx&31)];
            *(float4*)(smem + OFF_QROW + ((tx>>5)*132 + (tx&31)*4)*4) = v;
        }
    }
    __syncthreads();

    // ---- P1: W -> bf16 hi/lo split, in-place overlay (read regs, sync, write)
    {
        __attribute__((aligned(16))) float wreg[16];
        #pragma unroll
        for (int i = 0; i < 4; ++i)
            *(float4*)(wreg + 4*i) = ((float4*)smem)[4*tx + i];
        __syncthreads();
        short8 h0, l0, h1, l1;
        split8(wreg, h0, l0);
        split8(wreg + 8, h1, l1);
        const int r = tx >> 3, c0 = (tx & 7) * 16;
        unsigned short* Wh = (unsigned short*)smem;
        unsigned short* Wl = (unsigned short*)(smem + 17408);
        *(short8*)&Wh[r*136 + c0]     = h0;
        *(short8*)&Wh[r*136 + c0 + 8] = h1;
        *(short8*)&Wl[r*136 + c0]     = l0;
        *(short8*)&Wl[r*136 + c0 + 8] = l1;
    }
    __syncthreads();

    // ---- P2: hoist all W A-frags to registers (4 o-grps x 4 ksteps x h/l) ----
    short8 WAh[4][4], WAl[4][4];
    {
        const unsigned short* Wh = (const unsigned short*)smem;
        const unsigned short* Wl = (const unsigned short*)(smem + 17408);
        #pragma unroll
        for (int og = 0; og < 4; ++og)
            #pragma unroll
            for (int ks = 0; ks < 4; ++ks) {
                WAh[og][ks] = *(const short8*)&Wh[(16*og + c)*136 + 32*ks + 8*g];
                WAl[og][ks] = *(const short8*)&Wl[(16*og + c)*136 + 32*ks + 8*g];
            }
    }

    // ---- q-projection via MFMA (wave 0 only; cols c>=8 duplicate rows) ----
    if (w == 0) {
        f32x4 qa[4];
        #pragma unroll
        for (int og = 0; og < 4; ++og) qa[og] = (f32x4){0.f,0.f,0.f,0.f};
        const float* qrow = (const float*)(smem + OFF_QROW);
        #pragma unroll
        for (int ks = 0; ks < 4; ++ks) {
            __attribute__((aligned(16))) float qv[8];
            *(float4*)qv       = *(const float4*)&qrow[(c&7)*132 + 32*ks + 8*g];
            *(float4*)(qv + 4) = *(const float4*)&qrow[(c&7)*132 + 32*ks + 8*g + 4];
            short8 bh, bl;
            split8(qv, bh, bl);
            #pragma unroll
            for (int og = 0; og < 4; ++og) {
                qa[og] = __builtin_amdgcn_mfma_f32_16x16x32_bf16(WAh[og][ks], bh, qa[og], 0,0,0);
                qa[og] = __builtin_amdgcn_mfma_f32_16x16x32_bf16(WAh[og][ks], bl, qa[og], 0,0,0);
                qa[og] = __builtin_amdgcn_mfma_f32_16x16x32_bf16(WAl[og][ks], bh, qa[og], 0,0,0);
            }
        }
        float qn2a = 0.f;
        #pragma unroll
        for (int og = 0; og < 4; ++og)
            #pragma unroll
            for (int j = 0; j < 4; ++j) qn2a += qa[og][j]*qa[og][j];
        qn2a += __shfl_xor(qn2a, 16, 64);
        qn2a += __shfl_xor(qn2a, 32, 64);
        if (c < 8) {
            unsigned short* qph = (unsigned short*)(smem + OFF_QPH);
            unsigned short* qpl = (unsigned short*)(smem + OFF_QPL);
            #pragma unroll
            for (int og = 0; og < 4; ++og) {
                uint2 hi2, lo2;
                packpair(qa[og], hi2, lo2);
                *(uint2*)&qph[c*72 + 16*og + 4*g] = hi2;
                *(uint2*)&qpl[c*72 + 16*og + 4*g] = lo2;
            }
            if (g == 0) ((float*)(smem + OFF_QN2))[c] = qn2a;
        }
    }
    __syncthreads();

    // ---- hoist score A-frags (Qp split) + qn ----
    short8 Ash[2], Asl[2];
    {
        const unsigned short* qph = (const unsigned short*)(smem + OFF_QPH);
        const unsigned short* qpl = (const unsigned short*)(smem + OFF_QPL);
        #pragma unroll
        for (int ks2 = 0; ks2 < 2; ++ks2) {
            Ash[ks2] = *(const short8*)&qph[(c&7)*72 + 32*ks2 + 8*g];
            Asl[ks2] = *(const short8*)&qpl[(c&7)*72 + 32*ks2 + 8*g];
        }
    }
    float qn[4];
    {
        const float* qn2s = (const float*)(smem + OFF_QN2);
        #pragma unroll
        for (int j = 0; j < 4; ++j) qn[j] = qn2s[(4*g + j) & 7];
    }

    // ---- main loop: 8 chunks of 128 k-rows ----
    float s[8][4];
    unsigned short* kph = (unsigned short*)(smem + OFF_KPH);
    unsigned short* kpl = (unsigned short*)(smem + OFF_KPL);
    float* kn2c = (float*)(smem + OFF_KN2);

    #pragma unroll
    for (int ch = 0; ch < 8; ++ch) {
        // k-projection: wave w -> rows 16w..16w+15 (lane c = row)
        f32x4 ka[4];
        #pragma unroll
        for (int og = 0; og < 4; ++og) ka[og] = (f32x4){0.f,0.f,0.f,0.f};
        #pragma unroll
        for (int ks = 0; ks < 4; ++ks) {
            const float* kr = k + (size_t)(ch*128 + 16*w + c) * DIN + 32*ks + 8*g;
            __attribute__((aligned(16))) float kv[8];
            *(float4*)kv       = *(const float4*)kr;
            *(float4*)(kv + 4) = *(const float4*)(kr + 4);
            short8 bh, bl;
            split8(kv, bh, bl);
            #pragma unroll
            for (int og = 0; og < 4; ++og) {
                ka[og] = __builtin_amdgcn_mfma_f32_16x16x32_bf16(WAh[og][ks], bh, ka[og], 0,0,0);
                ka[og] = __builtin_amdgcn_mfma_f32_16x16x32_bf16(WAh[og][ks], bl, ka[og], 0,0,0);
                ka[og] = __builtin_amdgcn_mfma_f32_16x16x32_bf16(WAl[og][ks], bh, ka[og], 0,0,0);
            }
        }
        // lane(g,c) holds Kp[16og+4g+j][16w+c] -> split to LDS [m][o] + norm
        float kn2a = 0.f;
        #pragma unroll
        for (int og = 0; og < 4; ++og) {
            #pragma unroll
            for (int j = 0; j < 4; ++j) kn2a += ka[og][j]*ka[og][j];
            uint2 hi2, lo2;
            packpair(ka[og], hi2, lo2);
            *(uint2*)&kph[(16*w + c)*72 + 16*og + 4*g] = hi2;
            *(uint2*)&kpl[(16*w + c)*72 + 16*og + 4*g] = lo2;
        }
        kn2a += __shfl_xor(kn2a, 16, 64);
        kn2a += __shfl_xor(kn2a, 32, 64);
        if (g == 0) kn2c[16*w + c] = kn2a;
        __syncthreads();

        // score tile: wave w -> cols m = 16w + c of this chunk
        float knv = kn2c[16*w + c];
        f32x4 sa = (f32x4){0.f,0.f,0.f,0.f};
        #pragma unroll
        for (int ks2 = 0; ks2 < 2; ++ks2) {
            short8 bsh = *(const short8*)&kph[(16*w + c)*72 + 32*ks2 + 8*g];
            short8 bsl = *(const short8*)&kpl[(16*w + c)*72 + 32*ks2 + 8*g];
            sa = __builtin_amdgcn_mfma_f32_16x16x32_bf16(Ash[ks2], bsh, sa, 0,0,0);
            sa = __builtin_amdgcn_mfma_f32_16x16x32_bf16(Ash[ks2], bsl, sa, 0,0,0);
            sa = __builtin_amdgcn_mfma_f32_16x16x32_bf16(Asl[ks2], bsh, sa, 0,0,0);
        }
        #pragma unroll
        for (int j = 0; j < 4; ++j) {
            float d2 = fmaxf(qn[j] + knv - 2.f*sa[j], 0.f);
            s[ch][j] = -0.5f * sqrtf(d2);
        }
        __syncthreads();
    }

    // ---- softmax epilogue (R8-validated; rows 0-7 real on g<2) ----
    float* redmax = (float*)(smem + OFF_RMAX);
    float* redsum = (float*)(smem + OFF_RSUM);
    #pragma unroll
    for (int j = 0; j < 4; ++j) {
        float m8 = s[0][j];
        #pragma unroll
        for (int ch = 1; ch < 8; ++ch) m8 = fmaxf(m8, s[ch][j]);
        m8 = fmaxf(m8, __shfl_xor(m8, 1, 64));
        m8 = fmaxf(m8, __shfl_xor(m8, 2, 64));
        m8 = fmaxf(m8, __shfl_xor(m8, 4, 64));
        m8 = fmaxf(m8, __shfl_xor(m8, 8, 64));
        if (c == 0 && g < 2) redmax[(4*g + j)*8 + w] = m8;
    }
    __syncthreads();

    float mx[4];
    #pragma unroll
    for (int j = 0; j < 4; ++j) {
        const float* rm = redmax + ((4*g + j) & 7)*8;
        float m = rm[0];
        #pragma unroll
        for (int ww = 1; ww < 8; ++ww) m = fmaxf(m, rm[ww]);
        mx[j] = m;
    }

    #pragma unroll
    for (int j = 0; j < 4; ++j) {
        float t8 = 0.f;
        #pragma unroll
        for (int ch = 0; ch < 8; ++ch) {
            s[ch][j] = __expf(s[ch][j] - mx[j]);
            t8 += s[ch][j];
        }
        t8 += __shfl_xor(t8, 1, 64);
        t8 += __shfl_xor(t8, 2, 64);
        t8 += __shfl_xor(t8, 4, 64);
        t8 += __shfl_xor(t8, 8, 64);
        if (c == 0 && g < 2) redsum[(4*g + j)*8 + w] = t8;
    }
    __syncthreads();

    if (g < 2) {
        float inv[4];
        #pragma unroll
        for (int j = 0; j < 4; ++j) {
            const float* rs = redsum + (4*g + j)*8;
            float t = 0.f;
            #pragma unroll
            for (int ww = 0; ww < 8; ++ww) t += rs[ww];
            inv[j] = 1.0f / t;
        }
        #pragma unroll
        for (int ch = 0; ch < 8; ++ch)
            #pragma unroll
            for (int j = 0; j < 4; ++j)
                out[(size_t)(n0 + 4*g + j)*M_K + ch*128 + 16*w + c] = s[ch][j]*inv[j];
    }
}

extern "C" void kernel_launch(void* const* d_in, const int* in_sizes, int n_in,
                              void* d_out, int out_size, void* d_ws, size_t ws_size,
                              hipStream_t stream)
{
    const float* q = (const float*)d_in[0];
    const float* k = (const float*)d_in[1];
    const float* W = (const float*)d_in[2];
    float* out = (float*)d_out;

    fused_kernel<<<N_Q / 8, 512, 0, stream>>>(q, k, W, out);
}

// Round 10
// 23.277 us; speedup vs baseline: 1.4878x; 1.4878x over previous
//
#include <hip/hip_runtime.h>
#include <hip/hip_bf16.h>
#include <math.h>

#define N_Q 2048
#define M_K 1024
#define DIN 128
#define DK  64

typedef __attribute__((ext_vector_type(8))) short short8;
typedef __attribute__((ext_vector_type(4))) float f32x4;

// RNE bf16 hi/lo split of 8 fp32 -> two short8 frags (R9-validated)
static __device__ __forceinline__ void split8(const float* v, short8& h, short8& l)
{
    __attribute__((aligned(16))) unsigned int hu[4], lu[4];
    #pragma unroll
    for (int i = 0; i < 4; ++i) {
        __hip_bfloat16 h0 = __float2bfloat16(v[2*i]);
        __hip_bfloat16 h1 = __float2bfloat16(v[2*i+1]);
        float f0 = __bfloat162float(h0), f1 = __bfloat162float(h1);
        __hip_bfloat16 l0 = __float2bfloat16(v[2*i]   - f0);
        __hip_bfloat16 l1 = __float2bfloat16(v[2*i+1] - f1);
        hu[i] = (unsigned)*(unsigned short*)&h0 | ((unsigned)*(unsigned short*)&h1 << 16);
        lu[i] = (unsigned)*(unsigned short*)&l0 | ((unsigned)*(unsigned short*)&l1 << 16);
    }
    h = *(short8*)hu;
    l = *(short8*)lu;
}

// ---------------------------------------------------------------------------
// Kernel 1: MFMA projection (R9-validated algebra), fp32 outputs.
// 24 blocks x 512 thr (8 waves). Per block: stage W fp32 -> split to bf16
// hi/lo in LDS -> hoist all W A-frags to regs. Wave w owns 16-row tile
// t = bid*8+w (rows 16t..16t+15 of [q;k]); B-frags = row data split
// in-register from two global float4 loads; 12 MFMA per k-step
// (hh+hl+lh x 4 o-groups). D: lane(g,c), qa[og][j] = P[o=16og+4g+j][row=16t+c].
// Stores: Qp row-major [n][64] fp32 (float4 per og); KpT d-major [64][1024]
// fp32 (16 dwords, lanes c consecutive -> coalesced); exact-consistent norms.
// ---------------------------------------------------------------------------
__global__ __launch_bounds__(512) void proj_mfma_kernel(
    const float* __restrict__ q, const float* __restrict__ k,
    const float* __restrict__ W,
    float* __restrict__ Qp, float* __restrict__ KpT,
    float* __restrict__ qn2, float* __restrict__ kn2)
{
    __shared__ __align__(16) unsigned char smem[34816];   // W f32 32K, then Wh/Wl

    const int tx = threadIdx.x;
    const int w = tx >> 6, lane = tx & 63;
    const int g = lane >> 4, c = lane & 15;

    // P0: stage W fp32 linear (2048 float4s, 4/thread)
    {
        const float4* W4 = (const float4*)W;
        float4* Wst = (float4*)smem;
        #pragma unroll
        for (int i = 0; i < 4; ++i) Wst[tx + 512*i] = W4[tx + 512*i];
    }
    __syncthreads();

    // P1: W -> bf16 hi/lo split, in-place overlay (R9 verbatim)
    {
        __attribute__((aligned(16))) float wreg[16];
        #pragma unroll
        for (int i = 0; i < 4; ++i)
            *(float4*)(wreg + 4*i) = ((float4*)smem)[4*tx + i];
        __syncthreads();
        short8 h0, l0, h1, l1;
        split8(wreg, h0, l0);
        split8(wreg + 8, h1, l1);
        const int r = tx >> 3, c0 = (tx & 7) * 16;
        unsigned short* Wh = (unsigned short*)smem;
        unsigned short* Wl = (unsigned short*)(smem + 17408);
        *(short8*)&Wh[r*136 + c0]     = h0;
        *(short8*)&Wh[r*136 + c0 + 8] = h1;
        *(short8*)&Wl[r*136 + c0]     = l0;
        *(short8*)&Wl[r*136 + c0 + 8] = l1;
    }
    __syncthreads();

    // P2: hoist W A-frags (4 o-groups x 4 k-steps x hi/lo)
    short8 WAh[4][4], WAl[4][4];
    {
        const unsigned short* Wh = (const unsigned short*)smem;
        const unsigned short* Wl = (const unsigned short*)(smem + 17408);
        #pragma unroll
        for (int og = 0; og < 4; ++og)
            #pragma unroll
            for (int ks = 0; ks < 4; ++ks) {
                WAh[og][ks] = *(const short8*)&Wh[(16*og + c)*136 + 32*ks + 8*g];
                WAl[og][ks] = *(const short8*)&Wl[(16*og + c)*136 + 32*ks + 8*g];
            }
    }

    // tile t: rows 16t..16t+15 in [q;k] row space
    const int t = blockIdx.x * 8 + w;              // 0..191
    const int row = 16*t + c;                      // this lane's source row
    const float* src = (row < N_Q) ? (q + (size_t)row * DIN)
                                   : (k + (size_t)(row - N_Q) * DIN);

    f32x4 qa[4];
    #pragma unroll
    for (int og = 0; og < 4; ++og) qa[og] = (f32x4){0.f,0.f,0.f,0.f};

    #pragma unroll
    for (int ks = 0; ks < 4; ++ks) {
        __attribute__((aligned(16))) float rv[8];
        *(float4*)rv       = *(const float4*)(src + 32*ks + 8*g);
        *(float4*)(rv + 4) = *(const float4*)(src + 32*ks + 8*g + 4);
        short8 bh, bl;
        split8(rv, bh, bl);
        #pragma unroll
        for (int og = 0; og < 4; ++og) {
            qa[og] = __builtin_amdgcn_mfma_f32_16x16x32_bf16(WAh[og][ks], bh, qa[og], 0,0,0);
            qa[og] = __builtin_amdgcn_mfma_f32_16x16x32_bf16(WAh[og][ks], bl, qa[og], 0,0,0);
            qa[og] = __builtin_amdgcn_mfma_f32_16x16x32_bf16(WAl[og][ks], bh, qa[og], 0,0,0);
        }
    }

    // norm: partial over this lane's 16 o-dims, then sum over g (lane bits 4-5)
    float nrm = 0.f;
    #pragma unroll
    for (int og = 0; og < 4; ++og)
        #pragma unroll
        for (int j = 0; j < 4; ++j) nrm += qa[og][j]*qa[og][j];
    nrm += __shfl_xor(nrm, 16, 64);
    nrm += __shfl_xor(nrm, 32, 64);

    if (row < N_Q) {
        #pragma unroll
        for (int og = 0; og < 4; ++og)
            *(float4*)&Qp[(size_t)row * DK + 16*og + 4*g] = *(float4*)&qa[og];
        if (g == 0) qn2[row] = nrm;
    } else {
        const int m = row - N_Q;
        #pragma unroll
        for (int og = 0; og < 4; ++og)
            #pragma unroll
            for (int j = 0; j < 4; ++j)
                KpT[(size_t)(16*og + 4*g + j) * M_K + m] = qa[og][j];
        if (g == 0) kn2[m] = nrm;
    }
}

// ---------------------------------------------------------------------------
// Kernel 2 (R2 verbatim -- fastest measured): 256 blocks x 512 thr (8 waves).
// Block = 8 q-rows x all 1024 m. Thread tx owns cols {2tx,2tx+1}, acc[8][2].
// Coalesced float2 KpT reads; qpT d-major in LDS (broadcast b128 reads).
// Fused: dist^2 -> score -> row softmax (shuffle + LDS block reduce).
// ---------------------------------------------------------------------------
__global__ __launch_bounds__(512) void score_kernel(
    const float* __restrict__ Qp, const float* __restrict__ KpT,
    const float* __restrict__ qn2, const float* __restrict__ kn2,
    float* __restrict__ out)
{
    __shared__ float qpT[DK][8];
    __shared__ float qn2s[8];
    __shared__ float redmax[8][8];
    __shared__ float redsum[8][8];

    const int tx = threadIdx.x;
    const int n0 = blockIdx.x * 8;
    const int wave = tx >> 6, lane = tx & 63;

    {
        int r = tx & 7, d = tx >> 3;
        qpT[d][r] = Qp[(size_t)(n0 + r) * DK + d];
        if (tx < 8) qn2s[tx] = qn2[n0 + tx];
    }
    __syncthreads();

    float acc[8][2];
    #pragma unroll
    for (int r = 0; r < 8; ++r) { acc[r][0] = 0.f; acc[r][1] = 0.f; }

    const float2* K2 = (const float2*)KpT;
    #pragma unroll 8
    for (int d = 0; d < DK; ++d) {
        float2 kv = K2[d * (M_K / 2) + tx];
        float4 qa = *(const float4*)&qpT[d][0];
        float4 qb = *(const float4*)&qpT[d][4];
        float qv[8] = {qa.x, qa.y, qa.z, qa.w, qb.x, qb.y, qb.z, qb.w};
        #pragma unroll
        for (int r = 0; r < 8; ++r) {
            acc[r][0] = fmaf(qv[r], kv.x, acc[r][0]);
            acc[r][1] = fmaf(qv[r], kv.y, acc[r][1]);
        }
    }

    float2 kv2 = ((const float2*)kn2)[tx];
    float kn2a[2] = {kv2.x, kv2.y};
    #pragma unroll
    for (int r = 0; r < 8; ++r) {
        float qn = qn2s[r];
        #pragma unroll
        for (int i = 0; i < 2; ++i) {
            float d2 = fmaxf(fmaf(-2.f, acc[r][i], qn + kn2a[i]), 0.f);
            acc[r][i] = -0.5f * sqrtf(d2);
        }
    }

    #pragma unroll
    for (int r = 0; r < 8; ++r) {
        float m = fmaxf(acc[r][0], acc[r][1]);
        #pragma unroll
        for (int off = 32; off >= 1; off >>= 1)
            m = fmaxf(m, __shfl_xor(m, off, 64));
        if (lane == 0) redmax[r][wave] = m;
    }
    __syncthreads();

    float mx[8];
    #pragma unroll
    for (int r = 0; r < 8; ++r) {
        float4 a = *(const float4*)&redmax[r][0];
        float4 b = *(const float4*)&redmax[r][4];
        mx[r] = fmaxf(fmaxf(fmaxf(a.x, a.y), fmaxf(a.z, a.w)),
                      fmaxf(fmaxf(b.x, b.y), fmaxf(b.z, b.w)));
    }

    #pragma unroll
    for (int r = 0; r < 8; ++r) {
        acc[r][0] = __expf(acc[r][0] - mx[r]);
        acc[r][1] = __expf(acc[r][1] - mx[r]);
        float t = acc[r][0] + acc[r][1];
        #pragma unroll
        for (int off = 32; off >= 1; off >>= 1)
            t += __shfl_xor(t, off, 64);
        if (lane == 0) redsum[r][wave] = t;
    }
    __syncthreads();

    #pragma unroll
    for (int r = 0; r < 8; ++r) {
        float4 a = *(const float4*)&redsum[r][0];
        float4 b = *(const float4*)&redsum[r][4];
        float total = (a.x + a.y + a.z + a.w) + (b.x + b.y + b.z + b.w);
        float inv = 1.0f / total;
        float2 o = make_float2(acc[r][0] * inv, acc[r][1] * inv);
        ((float2*)out)[(size_t)(n0 + r) * (M_K / 2) + tx] = o;
    }
}

extern "C" void kernel_launch(void* const* d_in, const int* in_sizes, int n_in,
                              void* d_out, int out_size, void* d_ws, size_t ws_size,
                              hipStream_t stream)
{
    const float* q = (const float*)d_in[0];
    const float* k = (const float*)d_in[1];
    const float* W = (const float*)d_in[2];
    float* out = (float*)d_out;

    // ws layout (bytes): Qp 512K | KpT 256K | qn2 8K | kn2 4K
    unsigned char* base = (unsigned char*)d_ws;
    float* Qp  = (float*)base;
    float* KpT = (float*)(base + 524288);
    float* qn2 = (float*)(base + 786432);
    float* kn2 = (float*)(base + 794624);

    proj_mfma_kernel<<<24, 512, 0, stream>>>(q, k, W, Qp, KpT, qn2, kn2);
    score_kernel<<<N_Q / 8, 512, 0, stream>>>(Qp, KpT, qn2, kn2, out);
}